// Round 1
// baseline (425.975 us; speedup 1.0000x reference)
//
#include <hip/hip_runtime.h>
#include <math.h>

// Problem constants (match reference)
constexpr int D  = 64;   // input feature dim
constexpr int H  = 14;   // hidden dim (2*LAT)
constexpr int P  = 16;   // (LAT+1)*R
constexpr int LATc = 7;
constexpr int OUTW = 30; // 7 + 7 + 14 + 2
constexpr float SP_INV_1 = 0.5413248546129181f; // log(expm1(1))

// ---------------- SpMM 1: Y1[rows[e], :64] += vals[e] * X[cols[e], :64] ----
// one lane per (edge, feature); 64 lanes (one wave) per edge
__global__ void spmm1_kernel(const float* __restrict__ X,
                             const int* __restrict__ rows,
                             const int* __restrict__ cols,
                             const float* __restrict__ vals,
                             float* __restrict__ Y1, int E) {
    long long idx = (long long)blockIdx.x * blockDim.x + threadIdx.x;
    int e = (int)(idx >> 6);
    int f = (int)(idx & 63);
    if (e >= E) return;
    int r = rows[e];
    int c = cols[e];
    float v = vals[e];
    atomicAdd(&Y1[(size_t)r * D + f], v * X[(size_t)c * D + f]);
}

// ---------------- Dense 1: h1 = relu(Y1 @ W1), (N,64)@(64,14) --------------
__global__ void dense1_kernel(const float* __restrict__ Y1,
                              const float* __restrict__ W1,
                              float* __restrict__ h1, int N) {
    __shared__ float w[D * H];
    for (int i = threadIdx.x; i < D * H; i += blockDim.x) w[i] = W1[i];
    __syncthreads();
    int n = blockIdx.x * blockDim.x + threadIdx.x;
    if (n >= N) return;
    float acc[H];
#pragma unroll
    for (int j = 0; j < H; ++j) acc[j] = 0.f;
    const float4* xr = reinterpret_cast<const float4*>(Y1 + (size_t)n * D);
#pragma unroll
    for (int d4 = 0; d4 < D / 4; ++d4) {
        float4 x = xr[d4];
        float xs[4] = {x.x, x.y, x.z, x.w};
#pragma unroll
        for (int k = 0; k < 4; ++k) {
            int d = d4 * 4 + k;
#pragma unroll
            for (int j = 0; j < H; ++j) acc[j] = fmaf(xs[k], w[d * H + j], acc[j]);
        }
    }
    float* o = h1 + (size_t)n * H;
#pragma unroll
    for (int j = 0; j < H; ++j) o[j] = fmaxf(acc[j], 0.f);
}

// ---------------- SpMM 2: Y2[rows[e], :14] += vals[e] * h1[cols[e], :14] ---
// 16 lanes per edge (2 idle), 4 edges per wave
__global__ void spmm2_kernel(const float* __restrict__ h1,
                             const int* __restrict__ rows,
                             const int* __restrict__ cols,
                             const float* __restrict__ vals,
                             float* __restrict__ Y2, int E) {
    long long idx = (long long)blockIdx.x * blockDim.x + threadIdx.x;
    int e = (int)(idx >> 4);
    int f = (int)(idx & 15);
    if (e >= E || f >= H) return;
    int r = rows[e];
    int c = cols[e];
    float v = vals[e];
    atomicAdd(&Y2[(size_t)r * H + f], v * h1[(size_t)c * H + f]);
}

// ---------------- Fused tail: relu(Y2@W2) -> tanh heads -> output ----------
__global__ void final_kernel(const float* __restrict__ Y2,
                             const float* __restrict__ W2,
                             const float* __restrict__ Wd1,
                             const float* __restrict__ bd1,
                             const float* __restrict__ Wd2,
                             const float* __restrict__ bd2,
                             float* __restrict__ out, int N) {
    __shared__ float w2[H * H], wd1[H * H], wd2[H * P], b1[H], b2[P];
    for (int i = threadIdx.x; i < H * H; i += blockDim.x) { w2[i] = W2[i]; wd1[i] = Wd1[i]; }
    for (int i = threadIdx.x; i < H * P; i += blockDim.x) wd2[i] = Wd2[i];
    if (threadIdx.x < H) b1[threadIdx.x] = bd1[threadIdx.x];
    if (threadIdx.x < P) b2[threadIdx.x] = bd2[threadIdx.x];
    __syncthreads();
    int n = blockIdx.x * blockDim.x + threadIdx.x;
    if (n >= N) return;

    float y[H];
    const float* yr = Y2 + (size_t)n * H;
#pragma unroll
    for (int i = 0; i < H; ++i) y[i] = yr[i];

    float h[H];
#pragma unroll
    for (int j = 0; j < H; ++j) {
        float a = 0.f;
#pragma unroll
        for (int i = 0; i < H; ++i) a = fmaf(y[i], w2[i * H + j], a);
        h[j] = fmaxf(a, 0.f);
    }

    float pd[H];
#pragma unroll
    for (int j = 0; j < H; ++j) {
        float a = b1[j];
#pragma unroll
        for (int i = 0; i < H; ++i) a = fmaf(h[i], wd1[i * H + j], a);
        pd[j] = tanhf(a);
    }

    float pp[P];
#pragma unroll
    for (int j = 0; j < P; ++j) {
        float a = b2[j];
#pragma unroll
        for (int i = 0; i < H; ++i) a = fmaf(h[i], wd2[i * P + j], a);
        pp[j] = tanhf(a);
    }

    float* o = out + (size_t)n * OUTW;
#pragma unroll
    for (int k = 0; k < LATc; ++k) o[k] = pd[k];
#pragma unroll
    for (int k = 0; k < LATc; ++k) {
        float x = pd[LATc + k] + SP_INV_1;
        o[LATc + k] = log1pf(expf(x)); // softplus
    }
#pragma unroll
    for (int k = 0; k < H; ++k) o[14 + k] = pp[k];
    o[28] = pp[14];
    o[29] = pp[15];
}

extern "C" void kernel_launch(void* const* d_in, const int* in_sizes, int n_in,
                              void* d_out, int out_size, void* d_ws, size_t ws_size,
                              hipStream_t stream) {
    const float* X    = (const float*)d_in[0];
    const int*   rows = (const int*)d_in[1];
    const int*   cols = (const int*)d_in[2];
    const float* vals = (const float*)d_in[3];
    const float* W1   = (const float*)d_in[4];
    const float* W2   = (const float*)d_in[5];
    const float* Wd1  = (const float*)d_in[6];
    const float* bd1  = (const float*)d_in[7];
    const float* Wd2  = (const float*)d_in[8];
    const float* bd2  = (const float*)d_in[9];
    float* out = (float*)d_out;

    const int N = in_sizes[0] / D;   // 100000
    const int E = in_sizes[1];       // 1000000

    // workspace layout (fp32): Y1[N*64] | h1[N*14] | Y2[N*14]
    float* Y1 = (float*)d_ws;
    float* h1 = Y1 + (size_t)N * D;
    float* Y2 = h1 + (size_t)N * H;

    hipMemsetAsync(Y1, 0, (size_t)N * D * sizeof(float), stream);
    hipMemsetAsync(Y2, 0, (size_t)N * H * sizeof(float), stream);

    {
        long long threads = (long long)E * 64;
        int block = 256;
        unsigned grid = (unsigned)((threads + block - 1) / block);
        spmm1_kernel<<<grid, block, 0, stream>>>(X, rows, cols, vals, Y1, E);
    }
    {
        int block = 256;
        int grid = (N + block - 1) / block;
        dense1_kernel<<<grid, block, 0, stream>>>(Y1, W1, h1, N);
    }
    {
        long long threads = (long long)E * 16;
        int block = 256;
        unsigned grid = (unsigned)((threads + block - 1) / block);
        spmm2_kernel<<<grid, block, 0, stream>>>(h1, rows, cols, vals, Y2, E);
    }
    {
        int block = 256;
        int grid = (N + block - 1) / block;
        final_kernel<<<grid, block, 0, stream>>>(Y2, W2, Wd1, bd1, Wd2, bd2, out, N);
    }
}

// Round 3
// 298.773 us; speedup vs baseline: 1.4257x; 1.4257x over previous
//
#include <hip/hip_runtime.h>
#include <math.h>

// Problem constants (match reference)
constexpr int D  = 64;   // input feature dim
constexpr int H  = 14;   // hidden dim (2*LAT)
constexpr int P  = 16;   // (LAT+1)*R
constexpr int LATc = 7;
constexpr int OUTW = 30; // 7 + 7 + 14 + 2
constexpr float SP_INV_1 = 0.5413248546129181f; // log(expm1(1))

// ---------------- Dense: XW = X @ W1, (N,64)@(64,14) ----------------------
__global__ void dense_xw_kernel(const float* __restrict__ X,
                                const float* __restrict__ W1,
                                float* __restrict__ XW, int N) {
    __shared__ float w[D * H];
    for (int i = threadIdx.x; i < D * H; i += blockDim.x) w[i] = W1[i];
    __syncthreads();
    int n = blockIdx.x * blockDim.x + threadIdx.x;
    if (n >= N) return;
    float acc[H];
#pragma unroll
    for (int j = 0; j < H; ++j) acc[j] = 0.f;
    const float4* xr = reinterpret_cast<const float4*>(X + (size_t)n * D);
#pragma unroll
    for (int d4 = 0; d4 < D / 4; ++d4) {
        float4 x = xr[d4];
        float xs[4] = {x.x, x.y, x.z, x.w};
#pragma unroll
        for (int k = 0; k < 4; ++k) {
            int d = d4 * 4 + k;
#pragma unroll
            for (int j = 0; j < H; ++j) acc[j] = fmaf(xs[k], w[d * H + j], acc[j]);
        }
    }
    float* o = XW + (size_t)n * H;
#pragma unroll
    for (int j = 0; j < H; ++j) o[j] = acc[j];
}

// ---------------- SpMM (14-wide): Y[rows[e],:] += vals[e]*F[cols[e],:] -----
// 16 lanes per edge (2 idle), 4 edges per wave
__global__ void spmm14_kernel(const float* __restrict__ F,
                              const int* __restrict__ rows,
                              const int* __restrict__ cols,
                              const float* __restrict__ vals,
                              float* __restrict__ Y, int E) {
    long long idx = (long long)blockIdx.x * blockDim.x + threadIdx.x;
    int e = (int)(idx >> 4);
    int f = (int)(idx & 15);
    if (e >= E || f >= H) return;
    int r = rows[e];
    int c = cols[e];
    float v = vals[e];
    atomicAdd(&Y[(size_t)r * H + f], v * F[(size_t)c * H + f]);
}

// ---------------- Dense: HW = relu(Y1) @ W2, (N,14)@(14,14) ----------------
__global__ void dense_hw_kernel(const float* __restrict__ Y1,
                                const float* __restrict__ W2,
                                float* __restrict__ HW, int N) {
    __shared__ float w[H * H];
    for (int i = threadIdx.x; i < H * H; i += blockDim.x) w[i] = W2[i];
    __syncthreads();
    int n = blockIdx.x * blockDim.x + threadIdx.x;
    if (n >= N) return;
    float h[H];
    const float* yr = Y1 + (size_t)n * H;
#pragma unroll
    for (int i = 0; i < H; ++i) h[i] = fmaxf(yr[i], 0.f);
    float* o = HW + (size_t)n * H;
#pragma unroll
    for (int j = 0; j < H; ++j) {
        float a = 0.f;
#pragma unroll
        for (int i = 0; i < H; ++i) a = fmaf(h[i], w[i * H + j], a);
        o[j] = a;
    }
}

// ---------------- Fused tail: h2=relu(Y2) -> tanh heads -> output ----------
__global__ void final_kernel(const float* __restrict__ Y2,
                             const float* __restrict__ Wd1,
                             const float* __restrict__ bd1,
                             const float* __restrict__ Wd2,
                             const float* __restrict__ bd2,
                             float* __restrict__ out, int N) {
    __shared__ float wd1[H * H], wd2[H * P], b1[H], b2[P];
    for (int i = threadIdx.x; i < H * H; i += blockDim.x) wd1[i] = Wd1[i];
    for (int i = threadIdx.x; i < H * P; i += blockDim.x) wd2[i] = Wd2[i];
    if (threadIdx.x < H) b1[threadIdx.x] = bd1[threadIdx.x];
    if (threadIdx.x < P) b2[threadIdx.x] = bd2[threadIdx.x];
    __syncthreads();
    int n = blockIdx.x * blockDim.x + threadIdx.x;
    if (n >= N) return;

    float h[H];
    const float* yr = Y2 + (size_t)n * H;
#pragma unroll
    for (int i = 0; i < H; ++i) h[i] = fmaxf(yr[i], 0.f);

    float pd[H];
#pragma unroll
    for (int j = 0; j < H; ++j) {
        float a = b1[j];
#pragma unroll
        for (int i = 0; i < H; ++i) a = fmaf(h[i], wd1[i * H + j], a);
        pd[j] = tanhf(a);
    }

    float pp[P];
#pragma unroll
    for (int j = 0; j < P; ++j) {
        float a = b2[j];
#pragma unroll
        for (int i = 0; i < H; ++i) a = fmaf(h[i], wd2[i * P + j], a);
        pp[j] = tanhf(a);
    }

    float* o = out + (size_t)n * OUTW;
#pragma unroll
    for (int k = 0; k < LATc; ++k) o[k] = pd[k];
#pragma unroll
    for (int k = 0; k < LATc; ++k) {
        float x = pd[LATc + k] + SP_INV_1;
        o[LATc + k] = log1pf(expf(x)); // softplus
    }
#pragma unroll
    for (int k = 0; k < H; ++k) o[14 + k] = pp[k];
    o[28] = pp[14];
    o[29] = pp[15];
}

extern "C" void kernel_launch(void* const* d_in, const int* in_sizes, int n_in,
                              void* d_out, int out_size, void* d_ws, size_t ws_size,
                              hipStream_t stream) {
    const float* X    = (const float*)d_in[0];
    const int*   rows = (const int*)d_in[1];
    const int*   cols = (const int*)d_in[2];
    const float* vals = (const float*)d_in[3];
    const float* W1   = (const float*)d_in[4];
    const float* W2   = (const float*)d_in[5];
    const float* Wd1  = (const float*)d_in[6];
    const float* bd1  = (const float*)d_in[7];
    const float* Wd2  = (const float*)d_in[8];
    const float* bd2  = (const float*)d_in[9];
    float* out = (float*)d_out;

    const int N = in_sizes[0] / D;   // 100000
    const int E = in_sizes[1];       // 1000000

    // workspace layout (fp32): XW[N*14] | HW[N*14] | Y1[N*14] | Y2[N*14]
    float* XW = (float*)d_ws;
    float* HW = XW + (size_t)N * H;
    float* Y1 = HW + (size_t)N * H;
    float* Y2 = Y1 + (size_t)N * H;

    // zero both accumulators in one memset (they're adjacent)
    hipMemsetAsync(Y1, 0, (size_t)N * H * 2 * sizeof(float), stream);

    {
        int block = 256;
        int grid = (N + block - 1) / block;
        dense_xw_kernel<<<grid, block, 0, stream>>>(X, W1, XW, N);
    }
    {
        long long threads = (long long)E * 16;
        int block = 256;
        unsigned grid = (unsigned)((threads + block - 1) / block);
        spmm14_kernel<<<grid, block, 0, stream>>>(XW, rows, cols, vals, Y1, E);
    }
    {
        int block = 256;
        int grid = (N + block - 1) / block;
        dense_hw_kernel<<<grid, block, 0, stream>>>(Y1, W2, HW, N);
    }
    {
        long long threads = (long long)E * 16;
        int block = 256;
        unsigned grid = (unsigned)((threads + block - 1) / block);
        spmm14_kernel<<<grid, block, 0, stream>>>(HW, rows, cols, vals, Y2, E);
    }
    {
        int block = 256;
        int grid = (N + block - 1) / block;
        final_kernel<<<grid, block, 0, stream>>>(Y2, Wd1, bd1, Wd2, bd2, out, N);
    }
}